// Round 8
// baseline (734.153 us; speedup 1.0000x reference)
//
#include <hip/hip_runtime.h>
#include <hip/hip_fp16.h>
#include <math.h>

#define IN_DIM 256
#define HID 48
#define CLS 16
#define K_STEPS 10
#define ALPHA 0.1f

#define NBUC 256      // dst buckets (dst>>9: 512 nodes/bucket, 196 used)
#define NSPLIT 64     // edge chunks for multisplit
#define BSHIFT 9

// ---------------- utility ----------------

__global__ void zero_int_kernel(int* __restrict__ p, int n) {
    int i = blockIdx.x * blockDim.x + threadIdx.x;
    if (i < n) p[i] = 0;
}

__global__ void hist_kernel(const int* __restrict__ dst, int* __restrict__ deg, int nE) {
    int i = blockIdx.x * blockDim.x + threadIdx.x;
    if (i < nE) atomicAdd(&deg[dst[i]], 1);
}

__global__ void norm_kernel(const int* __restrict__ deg, float* __restrict__ nrm, int n) {
    int i = blockIdx.x * blockDim.x + threadIdx.x;
    if (i < n) nrm[i] = rsqrtf(fmaxf((float)deg[i], 1.0f));
}

// ---------------- exclusive scan over deg -> off, cursor ----------------

__global__ __launch_bounds__(256) void scan1_kernel(const int* __restrict__ deg,
                                                    int* __restrict__ bsum, int n) {
    __shared__ int ls[256];
    int t = threadIdx.x;
    int base = blockIdx.x * 1024 + t * 4;
    int s = 0;
    if (base + 3 < n) {
        int4 d = *(const int4*)(deg + base);
        s = d.x + d.y + d.z + d.w;
    } else {
        for (int i = 0; i < 4; i++) if (base + i < n) s += deg[base + i];
    }
    ls[t] = s; __syncthreads();
    for (int o = 128; o > 0; o >>= 1) {
        if (t < o) ls[t] += ls[t + o];
        __syncthreads();
    }
    if (t == 0) bsum[blockIdx.x] = ls[0];
}

__global__ void scan2_kernel(int* __restrict__ bsum, int* __restrict__ off, int nb, int n) {
    if (threadIdx.x == 0 && blockIdx.x == 0) {
        int run = 0;
        for (int i = 0; i < nb; i++) { int t = bsum[i]; bsum[i] = run; run += t; }
        off[n] = run;
    }
}

__global__ __launch_bounds__(256) void scan3_kernel(const int* __restrict__ deg,
                                                    const int* __restrict__ bsum,
                                                    int* __restrict__ off,
                                                    int* __restrict__ cursor, int n) {
    __shared__ int ts[256];
    int t = threadIdx.x;
    int base = blockIdx.x * 1024 + t * 4;
    int d0 = 0, d1 = 0, d2 = 0, d3 = 0;
    if (base + 3 < n) {
        int4 d = *(const int4*)(deg + base);
        d0 = d.x; d1 = d.y; d2 = d.z; d3 = d.w;
    } else {
        if (base     < n) d0 = deg[base];
        if (base + 1 < n) d1 = deg[base + 1];
        if (base + 2 < n) d2 = deg[base + 2];
        if (base + 3 < n) d3 = deg[base + 3];
    }
    int s = d0 + d1 + d2 + d3;
    ts[t] = s; __syncthreads();
    for (int o = 1; o < 256; o <<= 1) {
        int v = (t >= o) ? ts[t - o] : 0;
        __syncthreads();
        ts[t] += v;
        __syncthreads();
    }
    int ex = ts[t] - s + bsum[blockIdx.x];
    int p0 = ex, p1 = ex + d0, p2 = p1 + d1, p3 = p2 + d2;
    if (base     < n) { off[base]     = p0; cursor[base]     = p0; }
    if (base + 1 < n) { off[base + 1] = p1; cursor[base + 1] = p1; }
    if (base + 2 < n) { off[base + 2] = p2; cursor[base + 2] = p2; }
    if (base + 3 < n) { off[base + 3] = p3; cursor[base + 3] = p3; }
}

// ---------------- multisplit CSR fill (contention-free) ----------------
// A: per-chunk bucket histogram -> mtx[b][wg]
__global__ __launch_bounds__(256) void bhist_kernel(const int* __restrict__ dst,
                                                    int* __restrict__ mtx, int nE) {
    __shared__ int cnt[NBUC];
    int wg = blockIdx.x;
    for (int i = threadIdx.x; i < NBUC; i += 256) cnt[i] = 0;
    __syncthreads();
    int lo = (int)((long long)nE * wg / NSPLIT);
    int hi = (int)((long long)nE * (wg + 1) / NSPLIT);
    for (int i = lo + threadIdx.x; i < hi; i += 256)
        atomicAdd(&cnt[dst[i] >> BSHIFT], 1);
    __syncthreads();
    for (int b = threadIdx.x; b < NBUC; b += 256) mtx[b * NSPLIT + wg] = cnt[b];
}

// B: in-place scan: mtx[b][wg] -> global base for that (bucket, chunk)
__global__ __launch_bounds__(NBUC) void bscan_kernel(int* __restrict__ mtx) {
    __shared__ int ts[NBUC];
    int b = threadIdx.x;
    int base_i = b * NSPLIT;
    int s = 0;
    for (int w = 0; w < NSPLIT; w++) s += mtx[base_i + w];
    ts[b] = s; __syncthreads();
    for (int o = 1; o < NBUC; o <<= 1) {
        int v = (b >= o) ? ts[b - o] : 0;
        __syncthreads();
        ts[b] += v;
        __syncthreads();
    }
    int run = ts[b] - s;   // exclusive bucket base
    for (int w = 0; w < NSPLIT; w++) { int t = mtx[base_i + w]; mtx[base_i + w] = run; run += t; }
}

// C: scatter (dst,src) pairs into bucket-grouped ebuf
__global__ __launch_bounds__(256) void msplit_kernel(const int* __restrict__ src,
                                                     const int* __restrict__ dst,
                                                     const int* __restrict__ mtx,
                                                     int2* __restrict__ ebuf, int nE) {
    __shared__ int cur[NBUC];
    int wg = blockIdx.x;
    for (int b = threadIdx.x; b < NBUC; b += 256) cur[b] = mtx[b * NSPLIT + wg];
    __syncthreads();
    int lo = (int)((long long)nE * wg / NSPLIT);
    int hi = (int)((long long)nE * (wg + 1) / NSPLIT);
    for (int i = lo + threadIdx.x; i < hi; i += 256) {
        int d = dst[i];
        int p = atomicAdd(&cur[d >> BSHIFT], 1);
        ebuf[p] = make_int2(d, src[i]);
    }
}

// D: bucket-local fine fill (XCD-swizzled so a bucket's csrc lines stay in one L2)
__global__ __launch_bounds__(256) void ffill_kernel(const int2* __restrict__ ebuf,
                                                    int* __restrict__ cursor,
                                                    int* __restrict__ csrc, int nE) {
    int nwg = gridDim.x;                               // multiple of 8
    int wg = (blockIdx.x % 8) * (nwg / 8) + blockIdx.x / 8;
    int lo = (int)((long long)nE * wg / nwg);
    int hi = (int)((long long)nE * (wg + 1) / nwg);
    for (int i = lo + threadIdx.x; i < hi; i += 256) {
        int2 e = ebuf[i];
        int p = atomicAdd(&cursor[e.x], 1);
        csrc[p] = e.y;
    }
}

// ---------------- Wc = W2 @ W1 [16,256], bc = W2 @ b1 [16] ----------------

__global__ __launch_bounds__(256) void wc_kernel(
    const float* __restrict__ W1, const float* __restrict__ W2,
    const float* __restrict__ b1, float* __restrict__ Wc, float* __restrict__ bc)
{
    int c = blockIdx.x;
    int k = threadIdx.x;
    float acc = 0.0f;
    #pragma unroll
    for (int j = 0; j < HID; j++)
        acc = fmaf(W2[c * HID + j], W1[j * IN_DIM + k], acc);
    Wc[c * IN_DIM + k] = acc;
    if (k == 0) {
        float b = 0.0f;
        for (int j = 0; j < HID; j++) b = fmaf(W2[c * HID + j], b1[j], b);
        bc[c] = b;
    }
}

// ---------------- fused fc: z0 = X @ Wc^T + bc (f32); A = half(z0*nrm) ----------------

#define BM 128
#define BK 16
__global__ __launch_bounds__(256) void fcz_kernel(
    const float* __restrict__ X, const float* __restrict__ Wc,
    const float* __restrict__ bc, const float* __restrict__ nrm,
    float* __restrict__ z0, __half* __restrict__ A, int n)
{
    __shared__ float Xs[BK][BM + 1];
    __shared__ float Ws[BK][CLS];
    const int t = threadIdx.x;
    const int tx = t & 31;
    const int ty = t >> 5;
    const int mbase = blockIdx.x * BM;
    float acc[4][2] = {{0}};

    for (int k0 = 0; k0 < IN_DIM; k0 += BK) {
        #pragma unroll
        for (int c0 = 0; c0 < 2; c0++) {
            int c = t + c0 * 256;
            int m = c >> 2, kc = (c & 3) << 2;
            int gm = mbase + m;
            float4 xv = make_float4(0.f, 0.f, 0.f, 0.f);
            if (gm < n) xv = *(const float4*)(X + (size_t)gm * IN_DIM + k0 + kc);
            Xs[kc + 0][m] = xv.x; Xs[kc + 1][m] = xv.y;
            Xs[kc + 2][m] = xv.z; Xs[kc + 3][m] = xv.w;
        }
        if (t < 64) {
            int j = t >> 2, kc = (t & 3) << 2;
            float4 wv = *(const float4*)(Wc + (size_t)j * IN_DIM + k0 + kc);
            Ws[kc + 0][j] = wv.x; Ws[kc + 1][j] = wv.y;
            Ws[kc + 2][j] = wv.z; Ws[kc + 3][j] = wv.w;
        }
        __syncthreads();
        #pragma unroll
        for (int k = 0; k < BK; k++) {
            float a[4], b[2];
            #pragma unroll
            for (int im = 0; im < 4; im++) a[im] = Xs[k][tx + 32 * im];
            #pragma unroll
            for (int jn = 0; jn < 2; jn++) b[jn] = Ws[k][ty * 2 + jn];
            #pragma unroll
            for (int im = 0; im < 4; im++)
                #pragma unroll
                for (int jn = 0; jn < 2; jn++)
                    acc[im][jn] = fmaf(a[im], b[jn], acc[im][jn]);
        }
        __syncthreads();
    }

    #pragma unroll
    for (int im = 0; im < 4; im++) {
        int m = mbase + tx + 32 * im;
        if (m < n) {
            float nv = nrm[m];
            float r0 = acc[im][0] + bc[ty * 2 + 0];
            float r1 = acc[im][1] + bc[ty * 2 + 1];
            size_t idx = (size_t)m * CLS + ty * 2;
            z0[idx] = r0;
            z0[idx + 1] = r1;
            ((__half2*)A)[(size_t)m * 8 + ty] = __floats2half2_rn(r0 * nv, r1 * nv);
        }
    }
}

// ---------------- pull gather, 2 lanes/node, 16B loads, shfl-broadcast csrc ----

__device__ __forceinline__ float eluf(float x) {
    return x > 0.0f ? x : expm1f(x);
}

// raw = 8 halves (16B); add to 8 fp32 accumulators
__device__ __forceinline__ void hacc8(float4& x, float4& y, float4 raw) {
    __half2* h = reinterpret_cast<__half2*>(&raw);
    float2 f0 = __half22float2(h[0]);
    float2 f1 = __half22float2(h[1]);
    float2 f2 = __half22float2(h[2]);
    float2 f3 = __half22float2(h[3]);
    x.x += f0.x; x.y += f0.y; x.z += f1.x; x.w += f1.y;
    y.x += f2.x; y.y += f2.y; y.z += f3.x; y.w += f3.y;
}

template<int MODE>
__global__ __launch_bounds__(256) void gather2_kernel(
    const int* __restrict__ off, const int* __restrict__ csrc,
    const float4* __restrict__ A,      // half rows: 2 x 16B per node
    const float4* __restrict__ tele,   // f32 rows: 4 x 16B per node
    const float* __restrict__ nrm, const float* __restrict__ b2,
    float4* __restrict__ outpH, float4* __restrict__ x0out,
    float4* __restrict__ outf, int n)
{
    const int v = blockIdx.x * 128 + (threadIdx.x >> 1);
    if (v >= n) return;
    const int lane = threadIdx.x & 1;

    const int s = off[v], e = off[v + 1];
    float4 a0 = make_float4(0.f,0.f,0.f,0.f), a1 = a0, c0 = a0, c1 = a0;
    int i = s;
    // peel to int4 alignment
    for (; i < e && (i & 3); i++)
        hacc8(a0, a1, A[(size_t)csrc[i] * 2 + lane]);
    // main: 8 edges per iteration; lane0 loads idx i..i+3, lane1 i+4..i+7
    for (; i + 8 <= e; i += 8) {
        int4 me = *(const int4*)(csrc + i + 4 * lane);
        int4 ot;
        ot.x = __shfl_xor(me.x, 1); ot.y = __shfl_xor(me.y, 1);
        ot.z = __shfl_xor(me.z, 1); ot.w = __shfl_xor(me.w, 1);
        float4 r0 = A[(size_t)me.x * 2 + lane];
        float4 r1 = A[(size_t)me.y * 2 + lane];
        float4 r2 = A[(size_t)me.z * 2 + lane];
        float4 r3 = A[(size_t)me.w * 2 + lane];
        float4 r4 = A[(size_t)ot.x * 2 + lane];
        float4 r5 = A[(size_t)ot.y * 2 + lane];
        float4 r6 = A[(size_t)ot.z * 2 + lane];
        float4 r7 = A[(size_t)ot.w * 2 + lane];
        hacc8(a0, a1, r0); hacc8(c0, c1, r1);
        hacc8(a0, a1, r2); hacc8(c0, c1, r3);
        hacc8(a0, a1, r4); hacc8(c0, c1, r5);
        hacc8(a0, a1, r6); hacc8(c0, c1, r7);
    }
    for (; i < e; i++)
        hacc8(a0, a1, A[(size_t)csrc[i] * 2 + lane]);
    a0.x += c0.x; a0.y += c0.y; a0.z += c0.z; a0.w += c0.w;
    a1.x += c1.x; a1.y += c1.y; a1.z += c1.z; a1.w += c1.w;

    const float nv = nrm[v];
    const size_t ro = (size_t)v * 4 + 2 * lane;
    float4 h0 = tele[ro], h1 = tele[ro + 1];
    float4 r0, r1;
    r0.x = (1.0f - ALPHA) * a0.x * nv + ALPHA * h0.x;
    r0.y = (1.0f - ALPHA) * a0.y * nv + ALPHA * h0.y;
    r0.z = (1.0f - ALPHA) * a0.z * nv + ALPHA * h0.z;
    r0.w = (1.0f - ALPHA) * a0.w * nv + ALPHA * h0.w;
    r1.x = (1.0f - ALPHA) * a1.x * nv + ALPHA * h1.x;
    r1.y = (1.0f - ALPHA) * a1.y * nv + ALPHA * h1.y;
    r1.z = (1.0f - ALPHA) * a1.z * nv + ALPHA * h1.z;
    r1.w = (1.0f - ALPHA) * a1.w * nv + ALPHA * h1.w;

    if (MODE == 0) {
        float4 w;
        __half2* wh = reinterpret_cast<__half2*>(&w);
        wh[0] = __floats2half2_rn(r0.x * nv, r0.y * nv);
        wh[1] = __floats2half2_rn(r0.z * nv, r0.w * nv);
        wh[2] = __floats2half2_rn(r1.x * nv, r1.y * nv);
        wh[3] = __floats2half2_rn(r1.z * nv, r1.w * nv);
        outpH[(size_t)v * 2 + lane] = w;
    } else if (MODE == 1) {
        const float4* b2v = (const float4*)b2;
        float4 bb0 = b2v[2 * lane], bb1 = b2v[2 * lane + 1];
        float4 x0_, x1_;
        x0_.x = eluf(r0.x + bb0.x); x0_.y = eluf(r0.y + bb0.y);
        x0_.z = eluf(r0.z + bb0.z); x0_.w = eluf(r0.w + bb0.w);
        x1_.x = eluf(r1.x + bb1.x); x1_.y = eluf(r1.y + bb1.y);
        x1_.z = eluf(r1.z + bb1.z); x1_.w = eluf(r1.w + bb1.w);
        x0out[ro] = x0_; x0out[ro + 1] = x1_;
        float4 w;
        __half2* wh = reinterpret_cast<__half2*>(&w);
        wh[0] = __floats2half2_rn(x0_.x * nv, x0_.y * nv);
        wh[1] = __floats2half2_rn(x0_.z * nv, x0_.w * nv);
        wh[2] = __floats2half2_rn(x1_.x * nv, x1_.y * nv);
        wh[3] = __floats2half2_rn(x1_.z * nv, x1_.w * nv);
        outpH[(size_t)v * 2 + lane] = w;
    } else {
        float4 o0, o1;
        o0.x = eluf(r0.x); o0.y = eluf(r0.y); o0.z = eluf(r0.z); o0.w = eluf(r0.w);
        o1.x = eluf(r1.x); o1.y = eluf(r1.y); o1.z = eluf(r1.z); o1.w = eluf(r1.w);
        outf[ro] = o0; outf[ro + 1] = o1;
    }
}

// ---------------- launch ----------------

extern "C" void kernel_launch(void* const* d_in, const int* in_sizes, int n_in,
                              void* d_out, int out_size, void* d_ws, size_t ws_size,
                              hipStream_t stream)
{
    const float* features = (const float*)d_in[0];
    const int*   src      = (const int*)d_in[1];
    const int*   dst      = (const int*)d_in[2];
    const float* W1       = (const float*)d_in[3];
    const float* b1       = (const float*)d_in[4];
    const float* W2       = (const float*)d_in[5];
    const float* b2       = (const float*)d_in[6];
    float* out = (float*)d_out;

    const int n  = in_sizes[0] / IN_DIM;   // 100000
    const int nE = in_sizes[1];            // 1600000

    // ws layout (words):
    // f32: nrm[n] | z0[16n] | x0[16n] | Wc[4096] | bc[16]
    // f16: PH[16n] | QH[16n]  (8n words each)
    // int: deg[n] | off[n+4] | cursor[n] | bsum[1024] | csrc[nE] | mtx[NBUC*NSPLIT]
    // ebuf (int2, nE) aliases z0+x0 (dead before fcz writes z0)
    float* ws   = (float*)d_ws;
    float* nrm  = ws;
    float* z0   = nrm + n;
    float* x0   = z0 + (size_t)CLS * n;
    float* Wc   = x0 + (size_t)CLS * n;
    float* bc   = Wc + CLS * IN_DIM;
    __half* PH  = (__half*)(bc + 16);
    __half* QH  = PH + (size_t)CLS * n;
    int*   deg    = (int*)(QH + (size_t)CLS * n);
    int*   off    = deg + n;
    int*   cursor = off + n + 4;
    int*   bsum   = cursor + n;
    int*   csrc   = bsum + 1024;
    int*   mtx    = csrc + nE;
    int2*  ebuf   = (int2*)z0;

    const int B = 256;
    const int nb = (n + 1023) / 1024;

    // ---- degree, norm, CSR offsets ----
    zero_int_kernel<<<(n + B - 1) / B, B, 0, stream>>>(deg, n);
    hist_kernel<<<(nE + B - 1) / B, B, 0, stream>>>(dst, deg, nE);
    norm_kernel<<<(n + B - 1) / B, B, 0, stream>>>(deg, nrm, n);
    scan1_kernel<<<nb, 256, 0, stream>>>(deg, bsum, n);
    scan2_kernel<<<1, 64, 0, stream>>>(bsum, off, nb, n);
    scan3_kernel<<<nb, 256, 0, stream>>>(deg, bsum, off, cursor, n);

    // ---- multisplit CSR fill ----
    bhist_kernel<<<NSPLIT, 256, 0, stream>>>(dst, mtx, nE);
    bscan_kernel<<<1, NBUC, 0, stream>>>(mtx);
    msplit_kernel<<<NSPLIT, 256, 0, stream>>>(src, dst, mtx, ebuf, nE);
    ffill_kernel<<<256, 256, 0, stream>>>(ebuf, cursor, csrc, nE);

    // ---- combined fc (after ffill: ebuf region becomes z0) ----
    wc_kernel<<<CLS, 256, 0, stream>>>(W1, W2, b1, Wc, bc);
    fcz_kernel<<<(n + BM - 1) / BM, 256, 0, stream>>>(features, Wc, bc, nrm, z0, PH, n);

    int ggrid = (n + 127) / 128;

    // ---- propagation 1 (teleport z0); last step fuses +b2, ELU ----
    __half* pa = PH; __half* pb = QH;
    for (int k = 0; k < K_STEPS; k++) {
        if (k < K_STEPS - 1)
            gather2_kernel<0><<<ggrid, 256, 0, stream>>>(
                off, csrc, (const float4*)pa, (const float4*)z0, nrm, nullptr,
                (float4*)pb, nullptr, nullptr, n);
        else
            gather2_kernel<1><<<ggrid, 256, 0, stream>>>(
                off, csrc, (const float4*)pa, (const float4*)z0, nrm, b2,
                (float4*)pb, (float4*)x0, nullptr, n);
        __half* t = pa; pa = pb; pb = t;
    }

    // ---- propagation 2 (teleport x0); last step fuses ELU -> out ----
    for (int k = 0; k < K_STEPS; k++) {
        if (k < K_STEPS - 1)
            gather2_kernel<0><<<ggrid, 256, 0, stream>>>(
                off, csrc, (const float4*)pa, (const float4*)x0, nrm, nullptr,
                (float4*)pb, nullptr, nullptr, n);
        else
            gather2_kernel<2><<<ggrid, 256, 0, stream>>>(
                off, csrc, (const float4*)pa, (const float4*)x0, nrm, nullptr,
                nullptr, nullptr, (float4*)out, n);
        __half* t = pa; pa = pb; pb = t;
    }
}

// Round 9
// 677.644 us; speedup vs baseline: 1.0834x; 1.0834x over previous
//
#include <hip/hip_runtime.h>
#include <hip/hip_fp16.h>
#include <math.h>

#define IN_DIM 256
#define HID 48
#define CLS 16
#define K_STEPS 10
#define ALPHA 0.1f

// ---------------- utility ----------------

__global__ void zero_int_kernel(int* __restrict__ p, int n) {
    int i = blockIdx.x * blockDim.x + threadIdx.x;
    if (i < n) p[i] = 0;
}

__global__ void hist_kernel(const int* __restrict__ dst, int* __restrict__ deg, int nE) {
    int i = blockIdx.x * blockDim.x + threadIdx.x;
    if (i < nE) atomicAdd(&deg[dst[i]], 1);
}

__global__ void norm_kernel(const int* __restrict__ deg, float* __restrict__ nrm, int n) {
    int i = blockIdx.x * blockDim.x + threadIdx.x;
    if (i < n) nrm[i] = rsqrtf(fmaxf((float)deg[i], 1.0f));
}

// ---------------- exclusive scan over deg -> off, cursor ----------------

__global__ __launch_bounds__(256) void scan1_kernel(const int* __restrict__ deg,
                                                    int* __restrict__ bsum, int n) {
    __shared__ int ls[256];
    int t = threadIdx.x;
    int base = blockIdx.x * 1024 + t * 4;
    int s = 0;
    if (base + 3 < n) {
        int4 d = *(const int4*)(deg + base);
        s = d.x + d.y + d.z + d.w;
    } else {
        for (int i = 0; i < 4; i++) if (base + i < n) s += deg[base + i];
    }
    ls[t] = s; __syncthreads();
    for (int o = 128; o > 0; o >>= 1) {
        if (t < o) ls[t] += ls[t + o];
        __syncthreads();
    }
    if (t == 0) bsum[blockIdx.x] = ls[0];
}

__global__ void scan2_kernel(int* __restrict__ bsum, int* __restrict__ off, int nb, int n) {
    if (threadIdx.x == 0 && blockIdx.x == 0) {
        int run = 0;
        for (int i = 0; i < nb; i++) { int t = bsum[i]; bsum[i] = run; run += t; }
        off[n] = run;
    }
}

__global__ __launch_bounds__(256) void scan3_kernel(const int* __restrict__ deg,
                                                    const int* __restrict__ bsum,
                                                    int* __restrict__ off,
                                                    int* __restrict__ cursor, int n) {
    __shared__ int ts[256];
    int t = threadIdx.x;
    int base = blockIdx.x * 1024 + t * 4;
    int d0 = 0, d1 = 0, d2 = 0, d3 = 0;
    if (base + 3 < n) {
        int4 d = *(const int4*)(deg + base);
        d0 = d.x; d1 = d.y; d2 = d.z; d3 = d.w;
    } else {
        if (base     < n) d0 = deg[base];
        if (base + 1 < n) d1 = deg[base + 1];
        if (base + 2 < n) d2 = deg[base + 2];
        if (base + 3 < n) d3 = deg[base + 3];
    }
    int s = d0 + d1 + d2 + d3;
    ts[t] = s; __syncthreads();
    for (int o = 1; o < 256; o <<= 1) {
        int v = (t >= o) ? ts[t - o] : 0;
        __syncthreads();
        ts[t] += v;
        __syncthreads();
    }
    int ex = ts[t] - s + bsum[blockIdx.x];
    int p0 = ex, p1 = ex + d0, p2 = p1 + d1, p3 = p2 + d2;
    if (base     < n) { off[base]     = p0; cursor[base]     = p0; }
    if (base + 1 < n) { off[base + 1] = p1; cursor[base + 1] = p1; }
    if (base + 2 < n) { off[base + 2] = p2; cursor[base + 2] = p2; }
    if (base + 3 < n) { off[base + 3] = p3; cursor[base + 3] = p3; }
}

// ---------------- XCD-partitioned filtered CSR fill ----------------
// 8 groups (blockIdx&7 ~ XCD); each group scans ALL edges (coalesced reads)
// and commits only dst in its 1/8 node range -> csrc line writes and cursor
// atomics stay XCD-local (write-combined in that XCD's L2).

__global__ __launch_bounds__(256) void fill8_kernel(
    const int* __restrict__ src, const int* __restrict__ dst,
    int* __restrict__ cursor, int* __restrict__ csrc, int nE, int nper)
{
    const int g  = blockIdx.x & 7;
    const int bi = blockIdx.x >> 3;
    const int nb = gridDim.x >> 3;
    const int lo = g * nper, hi = lo + nper;   // node range owned by this group
    for (int i = bi * 256 + threadIdx.x; i < nE; i += nb * 256) {
        int d = dst[i];
        if (d >= lo && d < hi) {
            int p = atomicAdd(&cursor[d], 1);
            csrc[p] = src[i];
        }
    }
}

// ---------------- Wc = W2 @ W1 [16,256], bc = W2 @ b1 [16] ----------------

__global__ __launch_bounds__(256) void wc_kernel(
    const float* __restrict__ W1, const float* __restrict__ W2,
    const float* __restrict__ b1, float* __restrict__ Wc, float* __restrict__ bc)
{
    int c = blockIdx.x;
    int k = threadIdx.x;
    float acc = 0.0f;
    #pragma unroll
    for (int j = 0; j < HID; j++)
        acc = fmaf(W2[c * HID + j], W1[j * IN_DIM + k], acc);
    Wc[c * IN_DIM + k] = acc;
    if (k == 0) {
        float b = 0.0f;
        for (int j = 0; j < HID; j++) b = fmaf(W2[c * HID + j], b1[j], b);
        bc[c] = b;
    }
}

// ---------------- fused fc: z0 = X @ Wc^T + bc (f32); A = half(z0*nrm) ----------------

#define BM 128
#define BK 16
__global__ __launch_bounds__(256) void fcz_kernel(
    const float* __restrict__ X, const float* __restrict__ Wc,
    const float* __restrict__ bc, const float* __restrict__ nrm,
    float* __restrict__ z0, __half* __restrict__ A, int n)
{
    __shared__ float Xs[BK][BM + 1];
    __shared__ float Ws[BK][CLS];
    const int t = threadIdx.x;
    const int tx = t & 31;
    const int ty = t >> 5;
    const int mbase = blockIdx.x * BM;
    float acc[4][2] = {{0}};

    for (int k0 = 0; k0 < IN_DIM; k0 += BK) {
        #pragma unroll
        for (int c0 = 0; c0 < 2; c0++) {
            int c = t + c0 * 256;
            int m = c >> 2, kc = (c & 3) << 2;
            int gm = mbase + m;
            float4 xv = make_float4(0.f, 0.f, 0.f, 0.f);
            if (gm < n) xv = *(const float4*)(X + (size_t)gm * IN_DIM + k0 + kc);
            Xs[kc + 0][m] = xv.x; Xs[kc + 1][m] = xv.y;
            Xs[kc + 2][m] = xv.z; Xs[kc + 3][m] = xv.w;
        }
        if (t < 64) {
            int j = t >> 2, kc = (t & 3) << 2;
            float4 wv = *(const float4*)(Wc + (size_t)j * IN_DIM + k0 + kc);
            Ws[kc + 0][j] = wv.x; Ws[kc + 1][j] = wv.y;
            Ws[kc + 2][j] = wv.z; Ws[kc + 3][j] = wv.w;
        }
        __syncthreads();
        #pragma unroll
        for (int k = 0; k < BK; k++) {
            float a[4], b[2];
            #pragma unroll
            for (int im = 0; im < 4; im++) a[im] = Xs[k][tx + 32 * im];
            #pragma unroll
            for (int jn = 0; jn < 2; jn++) b[jn] = Ws[k][ty * 2 + jn];
            #pragma unroll
            for (int im = 0; im < 4; im++)
                #pragma unroll
                for (int jn = 0; jn < 2; jn++)
                    acc[im][jn] = fmaf(a[im], b[jn], acc[im][jn]);
        }
        __syncthreads();
    }

    #pragma unroll
    for (int im = 0; im < 4; im++) {
        int m = mbase + tx + 32 * im;
        if (m < n) {
            float nv = nrm[m];
            float r0 = acc[im][0] + bc[ty * 2 + 0];
            float r1 = acc[im][1] + bc[ty * 2 + 1];
            size_t idx = (size_t)m * CLS + ty * 2;
            z0[idx] = r0;
            z0[idx + 1] = r1;
            ((__half2*)A)[(size_t)m * 8 + ty] = __floats2half2_rn(r0 * nv, r1 * nv);
        }
    }
}

// ---------------- pull gather, 2 lanes/node, 16B loads, shfl-broadcast csrc ----

__device__ __forceinline__ float eluf(float x) {
    return x > 0.0f ? x : expm1f(x);
}

__device__ __forceinline__ void hacc8(float4& x, float4& y, float4 raw) {
    __half2* h = reinterpret_cast<__half2*>(&raw);
    float2 f0 = __half22float2(h[0]);
    float2 f1 = __half22float2(h[1]);
    float2 f2 = __half22float2(h[2]);
    float2 f3 = __half22float2(h[3]);
    x.x += f0.x; x.y += f0.y; x.z += f1.x; x.w += f1.y;
    y.x += f2.x; y.y += f2.y; y.z += f3.x; y.w += f3.y;
}

template<int MODE>
__global__ __launch_bounds__(256) void gather2_kernel(
    const int* __restrict__ off, const int* __restrict__ csrc,
    const float4* __restrict__ A,      // half rows: 2 x 16B per node
    const float4* __restrict__ tele,   // f32 rows: 4 x 16B per node
    const float* __restrict__ nrm, const float* __restrict__ b2,
    float4* __restrict__ outpH, float4* __restrict__ x0out,
    float4* __restrict__ outf, int n)
{
    const int v = blockIdx.x * 128 + (threadIdx.x >> 1);
    if (v >= n) return;
    const int lane = threadIdx.x & 1;

    const int s = off[v], e = off[v + 1];
    float4 a0 = make_float4(0.f,0.f,0.f,0.f), a1 = a0, c0 = a0, c1 = a0;
    int i = s;
    for (; i < e && (i & 3); i++)
        hacc8(a0, a1, A[(size_t)csrc[i] * 2 + lane]);
    for (; i + 8 <= e; i += 8) {
        int4 me = *(const int4*)(csrc + i + 4 * lane);
        int4 ot;
        ot.x = __shfl_xor(me.x, 1); ot.y = __shfl_xor(me.y, 1);
        ot.z = __shfl_xor(me.z, 1); ot.w = __shfl_xor(me.w, 1);
        float4 r0 = A[(size_t)me.x * 2 + lane];
        float4 r1 = A[(size_t)me.y * 2 + lane];
        float4 r2 = A[(size_t)me.z * 2 + lane];
        float4 r3 = A[(size_t)me.w * 2 + lane];
        float4 r4 = A[(size_t)ot.x * 2 + lane];
        float4 r5 = A[(size_t)ot.y * 2 + lane];
        float4 r6 = A[(size_t)ot.z * 2 + lane];
        float4 r7 = A[(size_t)ot.w * 2 + lane];
        hacc8(a0, a1, r0); hacc8(c0, c1, r1);
        hacc8(a0, a1, r2); hacc8(c0, c1, r3);
        hacc8(a0, a1, r4); hacc8(c0, c1, r5);
        hacc8(a0, a1, r6); hacc8(c0, c1, r7);
    }
    for (; i < e; i++)
        hacc8(a0, a1, A[(size_t)csrc[i] * 2 + lane]);
    a0.x += c0.x; a0.y += c0.y; a0.z += c0.z; a0.w += c0.w;
    a1.x += c1.x; a1.y += c1.y; a1.z += c1.z; a1.w += c1.w;

    const float nv = nrm[v];
    const size_t ro = (size_t)v * 4 + 2 * lane;
    float4 h0 = tele[ro], h1 = tele[ro + 1];
    float4 r0, r1;
    r0.x = (1.0f - ALPHA) * a0.x * nv + ALPHA * h0.x;
    r0.y = (1.0f - ALPHA) * a0.y * nv + ALPHA * h0.y;
    r0.z = (1.0f - ALPHA) * a0.z * nv + ALPHA * h0.z;
    r0.w = (1.0f - ALPHA) * a0.w * nv + ALPHA * h0.w;
    r1.x = (1.0f - ALPHA) * a1.x * nv + ALPHA * h1.x;
    r1.y = (1.0f - ALPHA) * a1.y * nv + ALPHA * h1.y;
    r1.z = (1.0f - ALPHA) * a1.z * nv + ALPHA * h1.z;
    r1.w = (1.0f - ALPHA) * a1.w * nv + ALPHA * h1.w;

    if (MODE == 0) {
        float4 w;
        __half2* wh = reinterpret_cast<__half2*>(&w);
        wh[0] = __floats2half2_rn(r0.x * nv, r0.y * nv);
        wh[1] = __floats2half2_rn(r0.z * nv, r0.w * nv);
        wh[2] = __floats2half2_rn(r1.x * nv, r1.y * nv);
        wh[3] = __floats2half2_rn(r1.z * nv, r1.w * nv);
        outpH[(size_t)v * 2 + lane] = w;
    } else if (MODE == 1) {
        const float4* b2v = (const float4*)b2;
        float4 bb0 = b2v[2 * lane], bb1 = b2v[2 * lane + 1];
        float4 x0_, x1_;
        x0_.x = eluf(r0.x + bb0.x); x0_.y = eluf(r0.y + bb0.y);
        x0_.z = eluf(r0.z + bb0.z); x0_.w = eluf(r0.w + bb0.w);
        x1_.x = eluf(r1.x + bb1.x); x1_.y = eluf(r1.y + bb1.y);
        x1_.z = eluf(r1.z + bb1.z); x1_.w = eluf(r1.w + bb1.w);
        x0out[ro] = x0_; x0out[ro + 1] = x1_;
        float4 w;
        __half2* wh = reinterpret_cast<__half2*>(&w);
        wh[0] = __floats2half2_rn(x0_.x * nv, x0_.y * nv);
        wh[1] = __floats2half2_rn(x0_.z * nv, x0_.w * nv);
        wh[2] = __floats2half2_rn(x1_.x * nv, x1_.y * nv);
        wh[3] = __floats2half2_rn(x1_.z * nv, x1_.w * nv);
        outpH[(size_t)v * 2 + lane] = w;
    } else {
        float4 o0, o1;
        o0.x = eluf(r0.x); o0.y = eluf(r0.y); o0.z = eluf(r0.z); o0.w = eluf(r0.w);
        o1.x = eluf(r1.x); o1.y = eluf(r1.y); o1.z = eluf(r1.z); o1.w = eluf(r1.w);
        outf[ro] = o0; outf[ro + 1] = o1;
    }
}

// ---------------- launch ----------------

extern "C" void kernel_launch(void* const* d_in, const int* in_sizes, int n_in,
                              void* d_out, int out_size, void* d_ws, size_t ws_size,
                              hipStream_t stream)
{
    const float* features = (const float*)d_in[0];
    const int*   src      = (const int*)d_in[1];
    const int*   dst      = (const int*)d_in[2];
    const float* W1       = (const float*)d_in[3];
    const float* b1       = (const float*)d_in[4];
    const float* W2       = (const float*)d_in[5];
    const float* b2       = (const float*)d_in[6];
    float* out = (float*)d_out;

    const int n  = in_sizes[0] / IN_DIM;   // 100000
    const int nE = in_sizes[1];            // 1600000

    // ws layout (words):
    // f32: nrm[n] | z0[16n] | x0[16n] | Wc[4096] | bc[16]
    // f16: PH[16n] | QH[16n]
    // int: deg[n] | off[n+4] | cursor[n] | bsum[1024] | csrc[nE]
    float* ws   = (float*)d_ws;
    float* nrm  = ws;
    float* z0   = nrm + n;
    float* x0   = z0 + (size_t)CLS * n;
    float* Wc   = x0 + (size_t)CLS * n;
    float* bc   = Wc + CLS * IN_DIM;
    __half* PH  = (__half*)(bc + 16);
    __half* QH  = PH + (size_t)CLS * n;
    int*   deg    = (int*)(QH + (size_t)CLS * n);
    int*   off    = deg + n;
    int*   cursor = off + n + 4;
    int*   bsum   = cursor + n;
    int*   csrc   = bsum + 1024;

    const int B = 256;
    const int nb = (n + 1023) / 1024;
    const int nper = (n + 7) / 8;          // nodes per XCD group

    // ---- degree, norm, CSR offsets ----
    zero_int_kernel<<<(n + B - 1) / B, B, 0, stream>>>(deg, n);
    hist_kernel<<<(nE + B - 1) / B, B, 0, stream>>>(dst, deg, nE);
    norm_kernel<<<(n + B - 1) / B, B, 0, stream>>>(deg, nrm, n);
    scan1_kernel<<<nb, 256, 0, stream>>>(deg, bsum, n);
    scan2_kernel<<<1, 64, 0, stream>>>(bsum, off, nb, n);
    scan3_kernel<<<nb, 256, 0, stream>>>(deg, bsum, off, cursor, n);

    // ---- XCD-partitioned filtered fill ----
    fill8_kernel<<<2048, 256, 0, stream>>>(src, dst, cursor, csrc, nE, nper);

    // ---- combined fc ----
    wc_kernel<<<CLS, 256, 0, stream>>>(W1, W2, b1, Wc, bc);
    fcz_kernel<<<(n + BM - 1) / BM, 256, 0, stream>>>(features, Wc, bc, nrm, z0, PH, n);

    int ggrid = (n + 127) / 128;

    // ---- propagation 1 (teleport z0); last step fuses +b2, ELU ----
    __half* pa = PH; __half* pb = QH;
    for (int k = 0; k < K_STEPS; k++) {
        if (k < K_STEPS - 1)
            gather2_kernel<0><<<ggrid, 256, 0, stream>>>(
                off, csrc, (const float4*)pa, (const float4*)z0, nrm, nullptr,
                (float4*)pb, nullptr, nullptr, n);
        else
            gather2_kernel<1><<<ggrid, 256, 0, stream>>>(
                off, csrc, (const float4*)pa, (const float4*)z0, nrm, b2,
                (float4*)pb, (float4*)x0, nullptr, n);
        __half* t = pa; pa = pb; pb = t;
    }

    // ---- propagation 2 (teleport x0); last step fuses ELU -> out ----
    for (int k = 0; k < K_STEPS; k++) {
        if (k < K_STEPS - 1)
            gather2_kernel<0><<<ggrid, 256, 0, stream>>>(
                off, csrc, (const float4*)pa, (const float4*)x0, nrm, nullptr,
                (float4*)pb, nullptr, nullptr, n);
        else
            gather2_kernel<2><<<ggrid, 256, 0, stream>>>(
                off, csrc, (const float4*)pa, (const float4*)x0, nrm, nullptr,
                nullptr, nullptr, (float4*)out, n);
        __half* t = pa; pa = pb; pb = t;
    }
}

// Round 10
// 565.327 us; speedup vs baseline: 1.2986x; 1.1987x over previous
//
#include <hip/hip_runtime.h>
#include <hip/hip_fp16.h>
#include <math.h>

#define IN_DIM 256
#define HID 48
#define CLS 16
#define K_STEPS 10
#define ALPHA 0.1f

// ---------------- utility ----------------

__global__ void zero_int_kernel(int* __restrict__ p, int n) {
    int i = blockIdx.x * blockDim.x + threadIdx.x;
    if (i < n) p[i] = 0;
}

__global__ void hist_kernel(const int* __restrict__ dst, int* __restrict__ deg, int nE) {
    int i = blockIdx.x * blockDim.x + threadIdx.x;
    if (i < nE) atomicAdd(&deg[dst[i]], 1);
}

__global__ void norm_kernel(const int* __restrict__ deg, float* __restrict__ nrm, int n) {
    int i = blockIdx.x * blockDim.x + threadIdx.x;
    if (i < n) nrm[i] = rsqrtf(fmaxf((float)deg[i], 1.0f));
}

// ---------------- exclusive scan over deg -> off, cursor ----------------

__global__ __launch_bounds__(256) void scan1_kernel(const int* __restrict__ deg,
                                                    int* __restrict__ bsum, int n) {
    __shared__ int ls[256];
    int t = threadIdx.x;
    int base = blockIdx.x * 1024 + t * 4;
    int s = 0;
    if (base + 3 < n) {
        int4 d = *(const int4*)(deg + base);
        s = d.x + d.y + d.z + d.w;
    } else {
        for (int i = 0; i < 4; i++) if (base + i < n) s += deg[base + i];
    }
    ls[t] = s; __syncthreads();
    for (int o = 128; o > 0; o >>= 1) {
        if (t < o) ls[t] += ls[t + o];
        __syncthreads();
    }
    if (t == 0) bsum[blockIdx.x] = ls[0];
}

__global__ void scan2_kernel(int* __restrict__ bsum, int* __restrict__ off, int nb, int n) {
    if (threadIdx.x == 0 && blockIdx.x == 0) {
        int run = 0;
        for (int i = 0; i < nb; i++) { int t = bsum[i]; bsum[i] = run; run += t; }
        off[n] = run;
    }
}

__global__ __launch_bounds__(256) void scan3_kernel(const int* __restrict__ deg,
                                                    const int* __restrict__ bsum,
                                                    int* __restrict__ off,
                                                    int* __restrict__ cursor, int n) {
    __shared__ int ts[256];
    int t = threadIdx.x;
    int base = blockIdx.x * 1024 + t * 4;
    int d0 = 0, d1 = 0, d2 = 0, d3 = 0;
    if (base + 3 < n) {
        int4 d = *(const int4*)(deg + base);
        d0 = d.x; d1 = d.y; d2 = d.z; d3 = d.w;
    } else {
        if (base     < n) d0 = deg[base];
        if (base + 1 < n) d1 = deg[base + 1];
        if (base + 2 < n) d2 = deg[base + 2];
        if (base + 3 < n) d3 = deg[base + 3];
    }
    int s = d0 + d1 + d2 + d3;
    ts[t] = s; __syncthreads();
    for (int o = 1; o < 256; o <<= 1) {
        int v = (t >= o) ? ts[t - o] : 0;
        __syncthreads();
        ts[t] += v;
        __syncthreads();
    }
    int ex = ts[t] - s + bsum[blockIdx.x];
    int p0 = ex, p1 = ex + d0, p2 = p1 + d1, p3 = p2 + d2;
    if (base     < n) { off[base]     = p0; cursor[base]     = p0; }
    if (base + 1 < n) { off[base + 1] = p1; cursor[base + 1] = p1; }
    if (base + 2 < n) { off[base + 2] = p2; cursor[base + 2] = p2; }
    if (base + 3 < n) { off[base + 3] = p3; cursor[base + 3] = p3; }
}

// ---------------- XCD-partitioned filtered CSR fill ----------------

__global__ __launch_bounds__(256) void fill8_kernel(
    const int* __restrict__ src, const int* __restrict__ dst,
    int* __restrict__ cursor, int* __restrict__ csrc, int nE, int nper)
{
    const int g  = blockIdx.x & 7;
    const int bi = blockIdx.x >> 3;
    const int nb = gridDim.x >> 3;
    const int lo = g * nper, hi = lo + nper;
    for (int i = bi * 256 + threadIdx.x; i < nE; i += nb * 256) {
        int d = dst[i];
        if (d >= lo && d < hi) {
            int p = atomicAdd(&cursor[d], 1);
            csrc[p] = src[i];
        }
    }
}

// ---------------- Wc = W2 @ W1 [16,256], bc = W2 @ b1 [16] ----------------

__global__ __launch_bounds__(256) void wc_kernel(
    const float* __restrict__ W1, const float* __restrict__ W2,
    const float* __restrict__ b1, float* __restrict__ Wc, float* __restrict__ bc)
{
    int c = blockIdx.x;
    int k = threadIdx.x;
    float acc = 0.0f;
    #pragma unroll
    for (int j = 0; j < HID; j++)
        acc = fmaf(W2[c * HID + j], W1[j * IN_DIM + k], acc);
    Wc[c * IN_DIM + k] = acc;
    if (k == 0) {
        float b = 0.0f;
        for (int j = 0; j < HID; j++) b = fmaf(W2[c * HID + j], b1[j], b);
        bc[c] = b;
    }
}

// ---------------- fused fc: z0 = X @ Wc^T + bc (f32); A = half(z0*nrm) ----------------

#define BM 128
#define BK 16
__global__ __launch_bounds__(256) void fcz_kernel(
    const float* __restrict__ X, const float* __restrict__ Wc,
    const float* __restrict__ bc, const float* __restrict__ nrm,
    float* __restrict__ z0, __half* __restrict__ A, int n)
{
    __shared__ float Xs[BK][BM + 1];
    __shared__ float Ws[BK][CLS];
    const int t = threadIdx.x;
    const int tx = t & 31;
    const int ty = t >> 5;
    const int mbase = blockIdx.x * BM;
    float acc[4][2] = {{0}};

    for (int k0 = 0; k0 < IN_DIM; k0 += BK) {
        #pragma unroll
        for (int c0 = 0; c0 < 2; c0++) {
            int c = t + c0 * 256;
            int m = c >> 2, kc = (c & 3) << 2;
            int gm = mbase + m;
            float4 xv = make_float4(0.f, 0.f, 0.f, 0.f);
            if (gm < n) xv = *(const float4*)(X + (size_t)gm * IN_DIM + k0 + kc);
            Xs[kc + 0][m] = xv.x; Xs[kc + 1][m] = xv.y;
            Xs[kc + 2][m] = xv.z; Xs[kc + 3][m] = xv.w;
        }
        if (t < 64) {
            int j = t >> 2, kc = (t & 3) << 2;
            float4 wv = *(const float4*)(Wc + (size_t)j * IN_DIM + k0 + kc);
            Ws[kc + 0][j] = wv.x; Ws[kc + 1][j] = wv.y;
            Ws[kc + 2][j] = wv.z; Ws[kc + 3][j] = wv.w;
        }
        __syncthreads();
        #pragma unroll
        for (int k = 0; k < BK; k++) {
            float a[4], b[2];
            #pragma unroll
            for (int im = 0; im < 4; im++) a[im] = Xs[k][tx + 32 * im];
            #pragma unroll
            for (int jn = 0; jn < 2; jn++) b[jn] = Ws[k][ty * 2 + jn];
            #pragma unroll
            for (int im = 0; im < 4; im++)
                #pragma unroll
                for (int jn = 0; jn < 2; jn++)
                    acc[im][jn] = fmaf(a[im], b[jn], acc[im][jn]);
        }
        __syncthreads();
    }

    #pragma unroll
    for (int im = 0; im < 4; im++) {
        int m = mbase + tx + 32 * im;
        if (m < n) {
            float nv = nrm[m];
            float r0 = acc[im][0] + bc[ty * 2 + 0];
            float r1 = acc[im][1] + bc[ty * 2 + 1];
            size_t idx = (size_t)m * CLS + ty * 2;
            z0[idx] = r0;
            z0[idx + 1] = r1;
            ((__half2*)A)[(size_t)m * 8 + ty] = __floats2half2_rn(r0 * nv, r1 * nv);
        }
    }
}

// ---------------- pull gather + fused combine (D=16, half storage) ----------------
// 4 lanes/node, 8B loads, all lanes of an instruction within one 32B row.
// csrc loaded as one int4 per 4 edges (broadcast across the 4 lanes).
// MODE 0: outp = half(r*nrm); MODE 1: x = elu(r+b2), x0 = x, outp = half(x*nrm);
// MODE 2: outf = elu(r).

struct __align__(8) half4 { __half2 a, b; };

__device__ __forceinline__ void hacc(float4& acc, half4 w) {
    float2 lo = __half22float2(w.a);
    float2 hi = __half22float2(w.b);
    acc.x += lo.x; acc.y += lo.y; acc.z += hi.x; acc.w += hi.y;
}
__device__ __forceinline__ float eluf(float x) {
    return x > 0.0f ? x : expm1f(x);
}

template<int MODE>
__global__ __launch_bounds__(256) void gatherh_kernel(
    const int* __restrict__ off, const int* __restrict__ csrc,
    const half4* __restrict__ A, const float4* __restrict__ tele,
    const float* __restrict__ nrm, const float4* __restrict__ b2v,
    half4* __restrict__ outp, float4* __restrict__ x0out,
    float4* __restrict__ outf, int n)
{
    const int v = blockIdx.x * 64 + threadIdx.y;
    if (v >= n) return;
    const int lane = threadIdx.x;        // 0..3

    const int s = off[v], e = off[v + 1];
    float4 a0 = make_float4(0.f, 0.f, 0.f, 0.f), a1 = a0;
    int i = s;
    // peel to 16B-aligned csrc index
    for (; i < e && (i & 3); i++)
        hacc(a0, A[(size_t)csrc[i] * 4 + lane]);
    // main: one int4 csrc load per 4 edges (same addr across lanes -> 1 request)
    for (; i + 4 <= e; i += 4) {
        int4 u = *(const int4*)(csrc + i);
        half4 w0 = A[(size_t)u.x * 4 + lane];
        half4 w1 = A[(size_t)u.y * 4 + lane];
        half4 w2 = A[(size_t)u.z * 4 + lane];
        half4 w3 = A[(size_t)u.w * 4 + lane];
        hacc(a0, w0); hacc(a1, w1); hacc(a0, w2); hacc(a1, w3);
    }
    for (; i < e; i++) hacc(a0, A[(size_t)csrc[i] * 4 + lane]);
    a0.x += a1.x; a0.y += a1.y; a0.z += a1.z; a0.w += a1.w;

    float nv = nrm[v];
    size_t o = (size_t)v * 4 + lane;
    float4 hv = tele[o];
    float4 r;
    r.x = (1.0f - ALPHA) * a0.x * nv + ALPHA * hv.x;
    r.y = (1.0f - ALPHA) * a0.y * nv + ALPHA * hv.y;
    r.z = (1.0f - ALPHA) * a0.z * nv + ALPHA * hv.z;
    r.w = (1.0f - ALPHA) * a0.w * nv + ALPHA * hv.w;

    if (MODE == 0) {
        half4 w;
        w.a = __floats2half2_rn(r.x * nv, r.y * nv);
        w.b = __floats2half2_rn(r.z * nv, r.w * nv);
        outp[o] = w;
    } else if (MODE == 1) {
        float4 b = b2v[lane];
        float4 x;
        x.x = eluf(r.x + b.x); x.y = eluf(r.y + b.y);
        x.z = eluf(r.z + b.z); x.w = eluf(r.w + b.w);
        x0out[o] = x;
        half4 w;
        w.a = __floats2half2_rn(x.x * nv, x.y * nv);
        w.b = __floats2half2_rn(x.z * nv, x.w * nv);
        outp[o] = w;
    } else {
        outf[o] = make_float4(eluf(r.x), eluf(r.y), eluf(r.z), eluf(r.w));
    }
}

// ---------------- launch ----------------

extern "C" void kernel_launch(void* const* d_in, const int* in_sizes, int n_in,
                              void* d_out, int out_size, void* d_ws, size_t ws_size,
                              hipStream_t stream)
{
    const float* features = (const float*)d_in[0];
    const int*   src      = (const int*)d_in[1];
    const int*   dst      = (const int*)d_in[2];
    const float* W1       = (const float*)d_in[3];
    const float* b1       = (const float*)d_in[4];
    const float* W2       = (const float*)d_in[5];
    const float* b2       = (const float*)d_in[6];
    float* out = (float*)d_out;

    const int n  = in_sizes[0] / IN_DIM;   // 100000
    const int nE = in_sizes[1];            // 1600000

    // ws layout (words):
    // f32: nrm[n] | z0[16n] | x0[16n] | Wc[4096] | bc[16]
    // f16: PH[16n] | QH[16n]
    // int: deg[n] | off[n+4] | cursor[n] | bsum[1024] | csrc[nE]
    float* ws   = (float*)d_ws;
    float* nrm  = ws;
    float* z0   = nrm + n;
    float* x0   = z0 + (size_t)CLS * n;
    float* Wc   = x0 + (size_t)CLS * n;
    float* bc   = Wc + CLS * IN_DIM;
    __half* PH  = (__half*)(bc + 16);
    __half* QH  = PH + (size_t)CLS * n;
    int*   deg    = (int*)(QH + (size_t)CLS * n);
    int*   off    = deg + n;
    int*   cursor = off + n + 4;
    int*   bsum   = cursor + n;
    int*   csrc   = bsum + 1024;           // word offset divisible by 4 -> 16B aligned

    const int B = 256;
    const int nb = (n + 1023) / 1024;
    const int nper = (n + 7) / 8;

    // ---- degree, norm, CSR offsets ----
    zero_int_kernel<<<(n + B - 1) / B, B, 0, stream>>>(deg, n);
    hist_kernel<<<(nE + B - 1) / B, B, 0, stream>>>(dst, deg, nE);
    norm_kernel<<<(n + B - 1) / B, B, 0, stream>>>(deg, nrm, n);
    scan1_kernel<<<nb, 256, 0, stream>>>(deg, bsum, n);
    scan2_kernel<<<1, 64, 0, stream>>>(bsum, off, nb, n);
    scan3_kernel<<<nb, 256, 0, stream>>>(deg, bsum, off, cursor, n);

    // ---- XCD-partitioned filtered fill ----
    fill8_kernel<<<2048, 256, 0, stream>>>(src, dst, cursor, csrc, nE, nper);

    // ---- combined fc ----
    wc_kernel<<<CLS, 256, 0, stream>>>(W1, W2, b1, Wc, bc);
    fcz_kernel<<<(n + BM - 1) / BM, 256, 0, stream>>>(features, Wc, bc, nrm, z0, PH, n);

    dim3 gblk(4, 64);
    int ggrid = (n + 63) / 64;

    // ---- propagation 1 (teleport z0); last step fuses +b2, ELU ----
    __half* pa = PH; __half* pb = QH;
    for (int k = 0; k < K_STEPS; k++) {
        if (k < K_STEPS - 1)
            gatherh_kernel<0><<<ggrid, gblk, 0, stream>>>(
                off, csrc, (const half4*)pa, (const float4*)z0, nrm,
                nullptr, (half4*)pb, nullptr, nullptr, n);
        else
            gatherh_kernel<1><<<ggrid, gblk, 0, stream>>>(
                off, csrc, (const half4*)pa, (const float4*)z0, nrm,
                (const float4*)b2, (half4*)pb, (float4*)x0, nullptr, n);
        __half* t = pa; pa = pb; pb = t;
    }

    // ---- propagation 2 (teleport x0); last step fuses ELU -> out ----
    for (int k = 0; k < K_STEPS; k++) {
        if (k < K_STEPS - 1)
            gatherh_kernel<0><<<ggrid, gblk, 0, stream>>>(
                off, csrc, (const half4*)pa, (const float4*)x0, nrm,
                nullptr, (half4*)pb, nullptr, nullptr, n);
        else
            gatherh_kernel<2><<<ggrid, gblk, 0, stream>>>(
                off, csrc, (const half4*)pa, (const float4*)x0, nrm,
                nullptr, nullptr, nullptr, (float4*)out, n);
        __half* t = pa; pa = pb; pb = t;
    }
}